// Round 1
// 643.755 us; speedup vs baseline: 1.0123x; 1.0123x over previous
//
#include <hip/hip_runtime.h>
#include <hip/hip_bf16.h>
#include <hip/hip_fp16.h>
#include <cstddef>

#define NEG_SLOPE 0.2f

typedef _Float16 half8 __attribute__((ext_vector_type(8)));
typedef float floatx4 __attribute__((ext_vector_type(4)));
typedef float floatx2 __attribute__((ext_vector_type(2)));

// ================= bucketed CSR build =================
// Bucket = 512 consecutive dst nodes. NB = ceil(N/512) (== 196 for N=100000, must be <= 256).
// part[] holds (src << 9) | (dst & 511) packed per edge, grouped by bucket.

// ---- fused: bucket histogram (blocks 0..511) + W1 transpose (512..639) + W2 transpose (640..671)
__global__ __launch_bounds__(256) void pre_k(const int* __restrict__ dst, int E,
                                             int* __restrict__ bhist, int NB,
                                             const float* __restrict__ W1, _Float16* __restrict__ W1T,
                                             const float* __restrict__ W2, _Float16* __restrict__ W2T) {
    int b = blockIdx.x;
    if (b < 512) {
        __shared__ int lh[256];
        for (int t = threadIdx.x; t < 256; t += 256) lh[t] = 0;
        __syncthreads();
        int per = (E + 511) / 512;
        int s = b * per;
        int e = min(s + per, E);
        for (int i = s + threadIdx.x; i < e; i += 256) atomicAdd(&lh[dst[i] >> 9], 1);
        __syncthreads();
        for (int t = threadIdx.x; t < NB; t += 256)
            if (lh[t]) atomicAdd(&bhist[t], lh[t]);
    } else if (b < 640) {
        int i = (b - 512) * 256 + threadIdx.x;  // 512*64 = 32768 elems, 128 blocks
        if (i < 512 * 64) {
            int k = i / 64, n = i % 64;
            W1T[(size_t)n * 512 + k] = (_Float16)W1[i];
        }
    } else {
        int i = (b - 640) * 256 + threadIdx.x;  // 64*128 = 8192 elems, 32 blocks
        if (i < 64 * 128) {
            int k = i / 128, n = i % 128;
            W2T[(size_t)n * 64 + k] = (_Float16)W2[i];
        }
    }
}

__global__ __launch_bounds__(256) void bucket_scan_k(const int* __restrict__ bhist, int NB,
                                                     int* __restrict__ bbase, int* __restrict__ cursor,
                                                     int* __restrict__ row_start, int N, int E) {
    __shared__ int tmp[256];
    int tid = threadIdx.x;
    int v = (tid < NB) ? bhist[tid] : 0;
    tmp[tid] = v;
    __syncthreads();
    for (int d = 1; d < 256; d <<= 1) {
        int t = tmp[tid];
        int a = (tid >= d) ? tmp[tid - d] : 0;
        __syncthreads();
        tmp[tid] = t + a;
        __syncthreads();
    }
    if (tid < NB) {
        int b = tmp[tid] - v;  // exclusive
        bbase[tid] = b;
        cursor[tid] = b;
    }
    if (tid == 0) {
        bbase[NB] = E;
        row_start[N] = E;
    }
}

// One workgroup per bucket: per-node counts + scan in LDS -> row_start; then scatter
// src ids into the bucket's contiguous csr window (L2-resident, ~64 KB).
__global__ __launch_bounds__(512) void bucket_build_k(const unsigned int* __restrict__ part,
                                                      const int* __restrict__ bbase,
                                                      int* __restrict__ row_start,
                                                      int* __restrict__ csr, int N) {
    __shared__ int cnt[512];
    __shared__ int cur[512];
    int b = blockIdx.x, tid = threadIdx.x;
    int n0 = b << 9;
    int s = bbase[b], e2 = bbase[b + 1];
    cnt[tid] = 0;
    __syncthreads();
    for (int i = s + tid; i < e2; i += 512) atomicAdd(&cnt[part[i] & 511], 1);
    __syncthreads();
    int v = cnt[tid];
    for (int d = 1; d < 512; d <<= 1) {  // inclusive scan, in place
        int t = cnt[tid];
        int a = (tid >= d) ? cnt[tid - d] : 0;
        __syncthreads();
        cnt[tid] = t + a;
        __syncthreads();
    }
    int excl = cnt[tid] - v;
    if (n0 + tid < N) row_start[n0 + tid] = s + excl;
    cur[tid] = excl;
    __syncthreads();
    for (int i = s + tid; i < e2; i += 512) {
        unsigned u = part[i];
        int p = atomicAdd(&cur[u & 511], 1);
        csr[s + p] = (int)(u >> 9);
    }
}

// ---------------- fused GEMM1 + partition -------------------------------------------
// Blocks 0..511: partition edges into bucket windows (needs bucket_scan done).
// Blocks 512..: GEMM1 (MFMA f16, fp32 acc): h1 = x @ W1, fused alpha1 epilogue.
// The two tasks are data-independent; fusion hides the partition pass under GEMM1.

__global__ __launch_bounds__(256) void gemm1_part_k(
    // gemm1 args
    const float* __restrict__ A, const _Float16* __restrict__ BT,
    const float* __restrict__ a_s, const float* __restrict__ a_d,
    __half* __restrict__ C, float* __restrict__ os, float* __restrict__ od, int M,
    // partition args
    const int* __restrict__ src, const int* __restrict__ dst, int E,
    int* __restrict__ cursor, unsigned int* __restrict__ part, int NB) {
    if (blockIdx.x < 512) {
        __shared__ int lh[256];
        __shared__ int lbase[256];
        for (int t = threadIdx.x; t < 256; t += 256) lh[t] = 0;
        __syncthreads();
        int per = (E + 511) / 512;
        int s = blockIdx.x * per;
        int e = min(s + per, E);
        for (int i = s + threadIdx.x; i < e; i += 256) atomicAdd(&lh[dst[i] >> 9], 1);
        __syncthreads();
        for (int t = threadIdx.x; t < NB; t += 256) {
            int c = lh[t];
            lbase[t] = c ? atomicAdd(&cursor[t], c) : 0;
            lh[t] = 0;  // becomes local cursor
        }
        __syncthreads();
        for (int i = s + threadIdx.x; i < e; i += 256) {
            int d = dst[i];
            int b = d >> 9;
            int lo = atomicAdd(&lh[b], 1);
            part[lbase[b] + lo] = ((unsigned)src[i] << 9) | (unsigned)(d & 511);
        }
        return;
    }
    // ---- GEMM1 body ----
    constexpr int NT = 4, K = 512, Nc = 64;
    int bid = blockIdx.x - 512;
    int wave = threadIdx.x >> 6, lane = threadIdx.x & 63;
    int m16 = lane & 15, quad = lane >> 4;
    int arow = bid * 64 + wave * 16 + m16;
    int arc = arow < M ? arow : M - 1;
    floatx4 acc[NT] = {};
    for (int k0 = 0; k0 < K; k0 += 32) {
        const float* ap = A + (size_t)arc * K + k0 + quad * 8;
        float4 v0 = *(const float4*)ap;
        float4 v1 = *(const float4*)(ap + 4);
        half8 af;
        af[0] = (_Float16)v0.x; af[1] = (_Float16)v0.y;
        af[2] = (_Float16)v0.z; af[3] = (_Float16)v0.w;
        af[4] = (_Float16)v1.x; af[5] = (_Float16)v1.y;
        af[6] = (_Float16)v1.z; af[7] = (_Float16)v1.w;
#pragma unroll
        for (int t = 0; t < NT; ++t) {
            half8 bf = *(const half8*)(BT + (size_t)(t * 16 + m16) * K + k0 + quad * 8);
            acc[t] = __builtin_amdgcn_mfma_f32_16x16x32_f16(af, bf, acc[t], 0, 0, 0);
        }
    }
    int gm0 = bid * 64 + wave * 16 + quad * 4;
    int head = (m16 >> 3);  // + 2t below
#pragma unroll
    for (int t = 0; t < NT; ++t) {
        float ws = a_s[(2 * t + head) * 8 + (m16 & 7)];
        float wd = a_d[(2 * t + head) * 8 + (m16 & 7)];
#pragma unroll
        for (int r = 0; r < 4; ++r) {
            int gm = gm0 + r;
            float v = acc[t][r];
            if (gm < M) C[(size_t)gm * Nc + t * 16 + m16] = __float2half(v);
            float s = v * ws, d = v * wd;
            s += __shfl_xor(s, 1, 64); d += __shfl_xor(d, 1, 64);
            s += __shfl_xor(s, 2, 64); d += __shfl_xor(d, 2, 64);
            s += __shfl_xor(s, 4, 64); d += __shfl_xor(d, 4, 64);
            if ((m16 & 7) == 0 && gm < M) {
                os[gm * 8 + 2 * t + head] = s;
                od[gm * 8 + 2 * t + head] = d;
            }
        }
    }
}

// ---------------- GEMM2 (MFMA f16, fp32 acc): h2 = h1o @ W2, fused alpha2 + fp8 pack
// NT=8 tiles cover Nc=128; tile t == head t. Epilogue: h2f8 (e4m3 pairs) store +
// as2/ad2 from fp32 acc (reduce over all 16 m16 lanes).

__global__ __launch_bounds__(256) void gemm2_k(const _Float16* __restrict__ A,
                                               const _Float16* __restrict__ BT,
                                               const float* __restrict__ a_s,
                                               const float* __restrict__ a_d,
                                               unsigned short* __restrict__ Cf8,
                                               float* __restrict__ os,
                                               float* __restrict__ od, int M) {
    constexpr int NT = 8, K = 64;
    int wave = threadIdx.x >> 6, lane = threadIdx.x & 63;
    int m16 = lane & 15, quad = lane >> 4;
    int arow = blockIdx.x * 64 + wave * 16 + m16;
    int arc = arow < M ? arow : M - 1;
    floatx4 acc[NT] = {};
    for (int k0 = 0; k0 < K; k0 += 32) {
        half8 af = *(const half8*)(A + (size_t)arc * K + k0 + quad * 8);
#pragma unroll
        for (int t = 0; t < NT; ++t) {
            half8 bf = *(const half8*)(BT + (size_t)(t * 16 + m16) * K + k0 + quad * 8);
            acc[t] = __builtin_amdgcn_mfma_f32_16x16x32_f16(af, bf, acc[t], 0, 0, 0);
        }
    }
    int gm0 = blockIdx.x * 64 + wave * 16 + quad * 4;
#pragma unroll
    for (int t = 0; t < NT; ++t) {
        float ws = a_s[t * 16 + m16];
        float wd = a_d[t * 16 + m16];
#pragma unroll
        for (int r = 0; r < 4; ++r) {
            int gm = gm0 + r;
            float v = acc[t][r];
            float o = __shfl_xor(v, 1, 64);  // neighboring column
            if (gm < M && !(m16 & 1)) {
                unsigned p = __builtin_amdgcn_cvt_pk_fp8_f32(v, o, 0, false);
                Cf8[(size_t)gm * 64 + t * 8 + (m16 >> 1)] = (unsigned short)(p & 0xffff);
            }
            float s = v * ws, d = v * wd;
            s += __shfl_xor(s, 1, 64); d += __shfl_xor(d, 1, 64);
            s += __shfl_xor(s, 2, 64); d += __shfl_xor(d, 2, 64);
            s += __shfl_xor(s, 4, 64); d += __shfl_xor(d, 4, 64);
            s += __shfl_xor(s, 8, 64); d += __shfl_xor(d, 8, 64);
            if (gm < M && m16 == t) {
                os[gm * 8 + t] = s;
                od[gm * 8 + t] = d;
            }
        }
    }
}

// ---------------- layer 1 aggregation: shuffle-free, 8B/lane gathers ---------------
// 256-thread block = 4 waves = 8 nodes. Per wave: 2 nodes (one per 32-lane half).
// Within a half: 2 edge-groups of 16 lanes (jj = ll>>4); lane k = ll&15 covers f16
// channels 4k..4k+3 (uint2 gather), head = k>>1. Each lane handles its own edges:
// no per-edge cross-lane shuffles. Group partials combined once via shfl_xor(16).

__global__ __launch_bounds__(256) void aggregate1_k(
    const uint2* __restrict__ H1, const float* __restrict__ as,
    const float* __restrict__ ad, const int* __restrict__ row_start,
    const int* __restrict__ csr, const float* __restrict__ b1,
    uint2* __restrict__ h1o, int N) {
    int l = threadIdx.x & 63;
    int wv = threadIdx.x >> 6;
    int ll = l & 31;
    int n = min((int)(blockIdx.x * 8 + wv * 2 + (l >> 5)), N - 1);
    int k = ll & 15;   // uint2 index within 128B row
    int jj = ll >> 4;  // edge-group 0/1
    int h = k >> 1;    // head

    float adv = ad[n * 8 + h];
    float e0 = as[n * 8 + h] + adv;
    e0 = fmaxf(e0, NEG_SLOPE * e0);
    float ex0 = __expf(e0);
    float x0 = jj ? 0.f : ex0;  // self loop counted once (group 0 only)

    uint2 sv = H1[(size_t)n * 16 + k];
    float2 s01 = __half22float2(*(const __half2*)&sv.x);
    float2 s23 = __half22float2(*(const __half2*)&sv.y);
    float denom = x0;
    float a0 = x0 * s01.x, a1 = x0 * s01.y, a2 = x0 * s23.x, a3 = x0 * s23.y;

    int e = row_start[n], end = row_start[n + 1];
    for (; e + 8 <= end; e += 8) {
#pragma unroll
        for (int u = 0; u < 4; ++u) {
            int sj = csr[e + 2 * u + jj];
            float t = as[sj * 8 + h] + adv;
            t = fmaxf(t, NEG_SLOPE * t);
            float x = __expf(t);
            uint2 gv = H1[(size_t)sj * 16 + k];
            float2 v01 = __half22float2(*(const __half2*)&gv.x);
            float2 v23 = __half22float2(*(const __half2*)&gv.y);
            denom += x;
            a0 = fmaf(x, v01.x, a0); a1 = fmaf(x, v01.y, a1);
            a2 = fmaf(x, v23.x, a2); a3 = fmaf(x, v23.y, a3);
        }
    }
    if (e < end) {  // predicated tail: covers up to 7 remaining edges
#pragma unroll
        for (int u = 0; u < 4; ++u) {
            int idx = e + 2 * u + jj;
            int sj = csr[min(idx, end - 1)];
            float t = as[sj * 8 + h] + adv;
            t = fmaxf(t, NEG_SLOPE * t);
            float x = idx < end ? __expf(t) : 0.f;
            uint2 gv = H1[(size_t)sj * 16 + k];
            float2 v01 = __half22float2(*(const __half2*)&gv.x);
            float2 v23 = __half22float2(*(const __half2*)&gv.y);
            denom += x;
            a0 = fmaf(x, v01.x, a0); a1 = fmaf(x, v01.y, a1);
            a2 = fmaf(x, v23.x, a2); a3 = fmaf(x, v23.y, a3);
        }
    }
    // combine the two edge-groups
    denom += __shfl_xor(denom, 16, 64);
    a0 += __shfl_xor(a0, 16, 64);
    a1 += __shfl_xor(a1, 16, 64);
    a2 += __shfl_xor(a2, 16, 64);
    a3 += __shfl_xor(a3, 16, 64);
    float inv = 1.f / denom;
    float r0 = a0 * inv + b1[4 * k + 0];
    float r1 = a1 * inv + b1[4 * k + 1];
    float r2 = a2 * inv + b1[4 * k + 2];
    float r3 = a3 * inv + b1[4 * k + 3];
    r0 = r0 > 0.f ? r0 : expm1f(r0);
    r1 = r1 > 0.f ? r1 : expm1f(r1);
    r2 = r2 > 0.f ? r2 : expm1f(r2);
    r3 = r3 > 0.f ? r3 : expm1f(r3);
    if (!jj) {
        __half2 p01 = __floats2half2_rn(r0, r1);
        __half2 p23 = __floats2half2_rn(r2, r3);
        uint2 o;
        o.x = *(const unsigned*)&p01;
        o.y = *(const unsigned*)&p23;
        h1o[(size_t)n * 16 + k] = o;
    }
}

// ---------------- layer 2 aggregation: shuffle-free, 8B/lane fp8 gathers -----------
// Lane k covers byte-channels 8k..8k+7 of the 128 B fp8 row; head = k>>1.
// Same group structure as aggregate1_k; epilogue adds the head-mean reduction.

__global__ __launch_bounds__(256) void aggregate2_k(
    const uint2* __restrict__ H2, const float* __restrict__ as,
    const float* __restrict__ ad, const int* __restrict__ row_start,
    const int* __restrict__ csr, const float* __restrict__ b2,
    float* __restrict__ out, int N) {
    int l = threadIdx.x & 63;
    int wv = threadIdx.x >> 6;
    int ll = l & 31;
    int n = min((int)(blockIdx.x * 8 + wv * 2 + (l >> 5)), N - 1);
    int k = ll & 15;
    int jj = ll >> 4;
    int h = k >> 1;

    float adv = ad[n * 8 + h];
    float e0 = as[n * 8 + h] + adv;
    e0 = fmaxf(e0, NEG_SLOPE * e0);
    float ex0 = __expf(e0);
    float x0 = jj ? 0.f : ex0;

    uint2 sv = H2[(size_t)n * 16 + k];
    floatx2 p01 = __builtin_amdgcn_cvt_pk_f32_fp8((int)sv.x, false);
    floatx2 p23 = __builtin_amdgcn_cvt_pk_f32_fp8((int)sv.x, true);
    floatx2 p45 = __builtin_amdgcn_cvt_pk_f32_fp8((int)sv.y, false);
    floatx2 p67 = __builtin_amdgcn_cvt_pk_f32_fp8((int)sv.y, true);
    float denom = x0;
    float a0 = x0 * p01[0], a1 = x0 * p01[1], a2 = x0 * p23[0], a3 = x0 * p23[1];
    float a4 = x0 * p45[0], a5 = x0 * p45[1], a6 = x0 * p67[0], a7 = x0 * p67[1];

    int e = row_start[n], end = row_start[n + 1];
    for (; e + 8 <= end; e += 8) {
#pragma unroll
        for (int u = 0; u < 4; ++u) {
            int sj = csr[e + 2 * u + jj];
            float t = as[sj * 8 + h] + adv;
            t = fmaxf(t, NEG_SLOPE * t);
            float x = __expf(t);
            uint2 gv = H2[(size_t)sj * 16 + k];
            floatx2 v01 = __builtin_amdgcn_cvt_pk_f32_fp8((int)gv.x, false);
            floatx2 v23 = __builtin_amdgcn_cvt_pk_f32_fp8((int)gv.x, true);
            floatx2 v45 = __builtin_amdgcn_cvt_pk_f32_fp8((int)gv.y, false);
            floatx2 v67 = __builtin_amdgcn_cvt_pk_f32_fp8((int)gv.y, true);
            denom += x;
            a0 = fmaf(x, v01[0], a0); a1 = fmaf(x, v01[1], a1);
            a2 = fmaf(x, v23[0], a2); a3 = fmaf(x, v23[1], a3);
            a4 = fmaf(x, v45[0], a4); a5 = fmaf(x, v45[1], a5);
            a6 = fmaf(x, v67[0], a6); a7 = fmaf(x, v67[1], a7);
        }
    }
    if (e < end) {  // predicated tail
#pragma unroll
        for (int u = 0; u < 4; ++u) {
            int idx = e + 2 * u + jj;
            int sj = csr[min(idx, end - 1)];
            float t = as[sj * 8 + h] + adv;
            t = fmaxf(t, NEG_SLOPE * t);
            float x = idx < end ? __expf(t) : 0.f;
            uint2 gv = H2[(size_t)sj * 16 + k];
            floatx2 v01 = __builtin_amdgcn_cvt_pk_f32_fp8((int)gv.x, false);
            floatx2 v23 = __builtin_amdgcn_cvt_pk_f32_fp8((int)gv.x, true);
            floatx2 v45 = __builtin_amdgcn_cvt_pk_f32_fp8((int)gv.y, false);
            floatx2 v67 = __builtin_amdgcn_cvt_pk_f32_fp8((int)gv.y, true);
            denom += x;
            a0 = fmaf(x, v01[0], a0); a1 = fmaf(x, v01[1], a1);
            a2 = fmaf(x, v23[0], a2); a3 = fmaf(x, v23[1], a3);
            a4 = fmaf(x, v45[0], a4); a5 = fmaf(x, v45[1], a5);
            a6 = fmaf(x, v67[0], a6); a7 = fmaf(x, v67[1], a7);
        }
    }
    // group-combine denom, normalize per-group partials, then sum groups+heads
    denom += __shfl_xor(denom, 16, 64);
    float inv = 1.f / denom;
    a0 *= inv; a1 *= inv; a2 *= inv; a3 *= inv;
    a4 *= inv; a5 *= inv; a6 *= inv; a7 *= inv;
#pragma unroll
    for (int m = 2; m <= 16; m <<= 1) {  // k bits 1..3 (heads) + bit 4 (groups)
        a0 += __shfl_xor(a0, m, 64);
        a1 += __shfl_xor(a1, m, 64);
        a2 += __shfl_xor(a2, m, 64);
        a3 += __shfl_xor(a3, m, 64);
        a4 += __shfl_xor(a4, m, 64);
        a5 += __shfl_xor(a5, m, 64);
        a6 += __shfl_xor(a6, m, 64);
        a7 += __shfl_xor(a7, m, 64);
    }
    if (ll < 2) {  // lane k=0 -> channels 0..7, k=1 -> channels 8..15
        int c0 = k * 8;
        float4 o0, o1;
        o0.x = a0 * 0.125f + b2[c0 + 0];
        o0.y = a1 * 0.125f + b2[c0 + 1];
        o0.z = a2 * 0.125f + b2[c0 + 2];
        o0.w = a3 * 0.125f + b2[c0 + 3];
        o1.x = a4 * 0.125f + b2[c0 + 4];
        o1.y = a5 * 0.125f + b2[c0 + 5];
        o1.z = a6 * 0.125f + b2[c0 + 6];
        o1.w = a7 * 0.125f + b2[c0 + 7];
        *(float4*)(out + (size_t)n * 16 + c0) = o0;
        *(float4*)(out + (size_t)n * 16 + c0 + 4) = o1;
    }
}

// ---------------- launch ----------------

extern "C" void kernel_launch(void* const* d_in, const int* in_sizes, int n_in,
                              void* d_out, int out_size, void* d_ws, size_t ws_size,
                              hipStream_t stream) {
    (void)n_in; (void)out_size; (void)ws_size;
    const float* x      = (const float*)d_in[0];
    const int*   ei     = (const int*)d_in[1];
    const float* W1     = (const float*)d_in[2];
    const float* a_src1 = (const float*)d_in[3];
    const float* a_dst1 = (const float*)d_in[4];
    const float* b1     = (const float*)d_in[5];
    const float* W2     = (const float*)d_in[6];
    const float* a_src2 = (const float*)d_in[7];
    const float* a_dst2 = (const float*)d_in[8];
    const float* b2     = (const float*)d_in[9];

    int N = in_sizes[0] / 512;
    int E = in_sizes[1] / 2;
    const int* src = ei;
    const int* dst = ei + E;
    int NB = (N + 511) >> 9;  // 196 for N=100000; LDS arrays assume <= 256

    char* ws = (char*)d_ws;
    size_t off = 0;
    auto alloc = [&](size_t bytes) -> void* {
        void* p = ws + off;
        off = (off + bytes + 255) & ~(size_t)255;
        return p;
    };
    __half* h1  = (__half*)alloc((size_t)N * 64 * 2);
    __half* h1o = (__half*)alloc((size_t)N * 64 * 2);
    unsigned short* h2f8 = (unsigned short*)alloc((size_t)N * 64 * 2);  // fp8 pairs
    float* as1  = (float*)alloc((size_t)N * 8 * 4);
    float* ad1  = (float*)alloc((size_t)N * 8 * 4);
    float* as2  = (float*)alloc((size_t)N * 8 * 4);
    float* ad2  = (float*)alloc((size_t)N * 8 * 4);
    _Float16* W1T = (_Float16*)alloc((size_t)512 * 64 * 2);
    _Float16* W2T = (_Float16*)alloc((size_t)64 * 128 * 2);
    int* row_start = (int*)alloc((size_t)(N + 1) * 4);
    int* bhist     = (int*)alloc(256 * 4);
    int* bbase     = (int*)alloc(257 * 4);
    int* cursor    = (int*)alloc(256 * 4);
    unsigned int* part = (unsigned int*)alloc((size_t)E * 4);
    int* csr       = (int*)alloc((size_t)E * 4);

    // --- fused hist + weight transposes ---
    hipMemsetAsync(bhist, 0, 256 * 4, stream);
    pre_k<<<672, 256, 0, stream>>>(dst, E, bhist, NB, W1, W1T, W2, W2T);
    bucket_scan_k<<<1, 256, 0, stream>>>(bhist, NB, bbase, cursor, row_start, N, E);

    int gblocks = (N + 63) / 64;
    int ablocks = (N + 7) / 8;

    // --- layer 1 GEMM fused with edge partition (independent tasks) ---
    gemm1_part_k<<<512 + gblocks, 256, 0, stream>>>(x, W1T, a_src1, a_dst1, h1, as1, ad1, N,
                                                    src, dst, E, cursor, part, NB);
    bucket_build_k<<<NB, 512, 0, stream>>>(part, bbase, row_start, csr, N);

    // --- layer 1 aggregation ---
    aggregate1_k<<<ablocks, 256, 0, stream>>>((const uint2*)h1, as1, ad1, row_start,
                                              csr, b1, (uint2*)h1o, N);

    // --- layer 2 ---
    gemm2_k<<<gblocks, 256, 0, stream>>>((const _Float16*)h1o, W2T, a_src2, a_dst2,
                                         h2f8, as2, ad2, N);
    aggregate2_k<<<ablocks, 256, 0, stream>>>((const uint2*)h2f8, as2, ad2,
                                              row_start, csr, b2, (float*)d_out, N);
}

// Round 2
// 626.828 us; speedup vs baseline: 1.0396x; 1.0270x over previous
//
#include <hip/hip_runtime.h>
#include <hip/hip_bf16.h>
#include <hip/hip_fp16.h>
#include <cstddef>

#define NEG_SLOPE 0.2f

typedef _Float16 half8 __attribute__((ext_vector_type(8)));
typedef float floatx4 __attribute__((ext_vector_type(4)));
typedef float floatx2 __attribute__((ext_vector_type(2)));

// ================= bucketed CSR build =================
// Bucket = 512 consecutive dst nodes. NB = ceil(N/512) (== 196 for N=100000, must be <= 256).
// part[] holds (src << 9) | (dst & 511) packed per edge, grouped by bucket.
// Per-block histograms are SAVED (bh_blocks) so partition needs no second pass and no
// global atomics: colscan_k turns them into exact per-(block,bucket) write bases.

// ---- fused: bucket histogram (blocks 0..511) + W1 transpose (512..639) + W2 transpose (640..671)
__global__ __launch_bounds__(256) void pre_k(const int* __restrict__ dst, int E,
                                             int* __restrict__ bhist, int* __restrict__ bh_blocks,
                                             int NB,
                                             const float* __restrict__ W1, _Float16* __restrict__ W1T,
                                             const float* __restrict__ W2, _Float16* __restrict__ W2T) {
    int b = blockIdx.x;
    if (b < 512) {
        __shared__ int lh[256];
        for (int t = threadIdx.x; t < 256; t += 256) lh[t] = 0;
        __syncthreads();
        int per = (E + 511) / 512;
        int s = b * per;
        int e = min(s + per, E);
        for (int i = s + threadIdx.x; i < e; i += 256) atomicAdd(&lh[dst[i] >> 9], 1);
        __syncthreads();
        for (int t = threadIdx.x; t < 256; t += 256) {
            int c = lh[t];
            bh_blocks[b * 256 + t] = c;
            if (c && t < NB) atomicAdd(&bhist[t], c);
        }
    } else if (b < 640) {
        int i = (b - 512) * 256 + threadIdx.x;  // 512*64 = 32768 elems, 128 blocks
        if (i < 512 * 64) {
            int k = i / 64, n = i % 64;
            W1T[(size_t)n * 512 + k] = (_Float16)W1[i];
        }
    } else {
        int i = (b - 640) * 256 + threadIdx.x;  // 64*128 = 8192 elems, 32 blocks
        if (i < 64 * 128) {
            int k = i / 128, n = i % 128;
            W2T[(size_t)n * 64 + k] = (_Float16)W2[i];
        }
    }
}

__global__ __launch_bounds__(256) void bucket_scan_k(const int* __restrict__ bhist, int NB,
                                                     int* __restrict__ bbase,
                                                     int* __restrict__ row_start, int N, int E) {
    __shared__ int tmp[256];
    int tid = threadIdx.x;
    int v = (tid < NB) ? bhist[tid] : 0;
    tmp[tid] = v;
    __syncthreads();
    for (int d = 1; d < 256; d <<= 1) {
        int t = tmp[tid];
        int a = (tid >= d) ? tmp[tid - d] : 0;
        __syncthreads();
        tmp[tid] = t + a;
        __syncthreads();
    }
    if (tid < NB) {
        bbase[tid] = tmp[tid] - v;  // exclusive
    }
    if (tid == 0) {
        bbase[NB] = E;
        row_start[N] = E;
    }
}

// One block per bucket t: exclusive scan over the 512 per-block counts of bucket t
// -> exact write base for (block b, bucket t). Removes all global atomics from partition.
__global__ __launch_bounds__(256) void colscan_k(const int* __restrict__ bh_blocks,
                                                 const int* __restrict__ bbase,
                                                 int* __restrict__ pbase) {
    __shared__ int ssum[256];
    int t = blockIdx.x;   // bucket
    int i = threadIdx.x;  // block-pair index (covers blocks 2i, 2i+1)
    int v0 = bh_blocks[(2 * i) * 256 + t];
    int v1 = bh_blocks[(2 * i + 1) * 256 + t];
    int s = v0 + v1;
    ssum[i] = s;
    __syncthreads();
    for (int d = 1; d < 256; d <<= 1) {
        int x = ssum[i];
        int a = (i >= d) ? ssum[i - d] : 0;
        __syncthreads();
        ssum[i] = x + a;
        __syncthreads();
    }
    int excl = ssum[i] - s + bbase[t];
    pbase[(2 * i) * 256 + t] = excl;
    pbase[(2 * i + 1) * 256 + t] = excl + v0;
}

// Single pass over this block's edge range; bases precomputed, only LDS-local cursors.
__global__ __launch_bounds__(256) void partition_k(const int* __restrict__ src,
                                                   const int* __restrict__ dst, int E,
                                                   const int* __restrict__ pbase,
                                                   unsigned int* __restrict__ part) {
    __shared__ int lbase[256];
    __shared__ int lh[256];
    int b = blockIdx.x;
    for (int t = threadIdx.x; t < 256; t += 256) {
        lbase[t] = pbase[b * 256 + t];
        lh[t] = 0;
    }
    __syncthreads();
    int per = (E + 511) / 512;
    int s = b * per;
    int e = min(s + per, E);
    for (int i = s + threadIdx.x; i < e; i += 256) {
        int d = dst[i];
        int bk = d >> 9;
        int lo = atomicAdd(&lh[bk], 1);
        part[lbase[bk] + lo] = ((unsigned)src[i] << 9) | (unsigned)(d & 511);
    }
}

// One workgroup per bucket: per-node counts + scan in LDS -> row_start; then scatter
// src ids into the bucket's contiguous csr window (L2-resident, ~64 KB).
__global__ __launch_bounds__(512) void bucket_build_k(const unsigned int* __restrict__ part,
                                                      const int* __restrict__ bbase,
                                                      int* __restrict__ row_start,
                                                      int* __restrict__ csr, int N) {
    __shared__ int cnt[512];
    __shared__ int cur[512];
    int b = blockIdx.x, tid = threadIdx.x;
    int n0 = b << 9;
    int s = bbase[b], e2 = bbase[b + 1];
    cnt[tid] = 0;
    __syncthreads();
    for (int i = s + tid; i < e2; i += 512) atomicAdd(&cnt[part[i] & 511], 1);
    __syncthreads();
    int v = cnt[tid];
    for (int d = 1; d < 512; d <<= 1) {  // inclusive scan, in place
        int t = cnt[tid];
        int a = (tid >= d) ? cnt[tid - d] : 0;
        __syncthreads();
        cnt[tid] = t + a;
        __syncthreads();
    }
    int excl = cnt[tid] - v;
    if (n0 + tid < N) row_start[n0 + tid] = s + excl;
    cur[tid] = excl;
    __syncthreads();
    for (int i = s + tid; i < e2; i += 512) {
        unsigned u = part[i];
        int p = atomicAdd(&cur[u & 511], 1);
        csr[s + p] = (int)(u >> 9);
    }
}

// ---------------- GEMM1: h1 = x @ W1 (f16 MFMA, fp32 acc), LDS double-buffered ------
// 128 rows/block (4 waves x 32 rows), K-step 64. W1T K-slice staged in XOR-swizzled
// LDS (conflict-free ds_read_b128 / ds_write_b128). A + B for step s+1 issued before
// compute of step s; single barrier per step. Fused alpha1 epilogue.

__global__ __launch_bounds__(256) void gemm1_k(const float* __restrict__ A,
                                               const _Float16* __restrict__ BT,
                                               const float* __restrict__ a_s,
                                               const float* __restrict__ a_d,
                                               __half* __restrict__ C,
                                               float* __restrict__ os,
                                               float* __restrict__ od, int M) {
    constexpr int K = 512;
    __shared__ __align__(16) _Float16 Bs[2][64 * 64];  // [col][64 k-halves], 8 KB per buf
    int tid = threadIdx.x;
    int wave = tid >> 6, lane = tid & 63;
    int m16 = lane & 15, quad = lane >> 4;
    int row0 = blockIdx.x * 128 + wave * 32;
    int r0 = min(row0 + m16, M - 1);
    int r1 = min(row0 + 16 + m16, M - 1);
    const float* a0p = A + (size_t)r0 * K + quad * 8;
    const float* a1p = A + (size_t)r1 * K + quad * 8;

    // B staging: thread -> row brow (0..63), colblock bcb (0..3) = 2x half8 per step.
    int brow = tid >> 2;
    int bcb = tid & 3;
    const _Float16* bsrc = BT + (size_t)brow * K + bcb * 16;
    int du0 = ((bcb * 2 + 0) * 8) ^ ((brow & 7) << 3);  // swizzled half-offsets
    int du1 = ((bcb * 2 + 1) * 8) ^ ((brow & 7) << 3);
    int dbase = brow * 64;

    floatx4 acc[2][4] = {};
    // ---- prologue: load + stage step 0 ----
    half8 b0 = *(const half8*)(bsrc + 0);
    half8 b1 = *(const half8*)(bsrc + 8);
    float4 a00 = *(const float4*)(a0p + 0);
    float4 a01 = *(const float4*)(a0p + 4);
    float4 a02 = *(const float4*)(a0p + 32);
    float4 a03 = *(const float4*)(a0p + 36);
    float4 a10 = *(const float4*)(a1p + 0);
    float4 a11 = *(const float4*)(a1p + 4);
    float4 a12 = *(const float4*)(a1p + 32);
    float4 a13 = *(const float4*)(a1p + 36);
    *(half8*)(&Bs[0][0] + dbase + du0) = b0;
    *(half8*)(&Bs[0][0] + dbase + du1) = b1;
    __syncthreads();

    int cur = 0;
    for (int s = 0; s < 8; ++s) {
        // convert this step's A to f16 fragments
        half8 af[2][2];
        af[0][0][0] = (_Float16)a00.x; af[0][0][1] = (_Float16)a00.y;
        af[0][0][2] = (_Float16)a00.z; af[0][0][3] = (_Float16)a00.w;
        af[0][0][4] = (_Float16)a01.x; af[0][0][5] = (_Float16)a01.y;
        af[0][0][6] = (_Float16)a01.z; af[0][0][7] = (_Float16)a01.w;
        af[0][1][0] = (_Float16)a02.x; af[0][1][1] = (_Float16)a02.y;
        af[0][1][2] = (_Float16)a02.z; af[0][1][3] = (_Float16)a02.w;
        af[0][1][4] = (_Float16)a03.x; af[0][1][5] = (_Float16)a03.y;
        af[0][1][6] = (_Float16)a03.z; af[0][1][7] = (_Float16)a03.w;
        af[1][0][0] = (_Float16)a10.x; af[1][0][1] = (_Float16)a10.y;
        af[1][0][2] = (_Float16)a10.z; af[1][0][3] = (_Float16)a10.w;
        af[1][0][4] = (_Float16)a11.x; af[1][0][5] = (_Float16)a11.y;
        af[1][0][6] = (_Float16)a11.z; af[1][0][7] = (_Float16)a11.w;
        af[1][1][0] = (_Float16)a12.x; af[1][1][1] = (_Float16)a12.y;
        af[1][1][2] = (_Float16)a12.z; af[1][1][3] = (_Float16)a12.w;
        af[1][1][4] = (_Float16)a13.x; af[1][1][5] = (_Float16)a13.y;
        af[1][1][6] = (_Float16)a13.z; af[1][1][7] = (_Float16)a13.w;
        if (s < 7) {  // issue next step's loads early; they fly under the MFMAs
            int k1 = (s + 1) * 64;
            b0 = *(const half8*)(bsrc + k1);
            b1 = *(const half8*)(bsrc + k1 + 8);
            a00 = *(const float4*)(a0p + k1);
            a01 = *(const float4*)(a0p + k1 + 4);
            a02 = *(const float4*)(a0p + k1 + 32);
            a03 = *(const float4*)(a0p + k1 + 36);
            a10 = *(const float4*)(a1p + k1);
            a11 = *(const float4*)(a1p + k1 + 4);
            a12 = *(const float4*)(a1p + k1 + 32);
            a13 = *(const float4*)(a1p + k1 + 36);
        }
        const _Float16* bsC = &Bs[cur][0];
#pragma unroll
        for (int t = 0; t < 4; ++t) {
#pragma unroll
            for (int kk = 0; kk < 2; ++kk) {
                int idx = (t * 16 + m16) * 64 + ((kk * 32 + quad * 8) ^ ((m16 & 7) << 3));
                half8 bf = *(const half8*)(bsC + idx);
                acc[0][t] = __builtin_amdgcn_mfma_f32_16x16x32_f16(af[0][kk], bf, acc[0][t], 0, 0, 0);
                acc[1][t] = __builtin_amdgcn_mfma_f32_16x16x32_f16(af[1][kk], bf, acc[1][t], 0, 0, 0);
            }
        }
        if (s < 7) {  // write-late staging of step s+1 into the other buffer
            _Float16* bsN = &Bs[cur ^ 1][0];
            *(half8*)(bsN + dbase + du0) = b0;
            *(half8*)(bsN + dbase + du1) = b1;
        }
        __syncthreads();
        cur ^= 1;
    }

    // ---- epilogue: C store + fused alpha1 ----
    int head = (m16 >> 3);  // + 2t below
#pragma unroll
    for (int rt = 0; rt < 2; ++rt) {
        int gmb = row0 + rt * 16 + quad * 4;
#pragma unroll
        for (int t = 0; t < 4; ++t) {
            float ws = a_s[(2 * t + head) * 8 + (m16 & 7)];
            float wd = a_d[(2 * t + head) * 8 + (m16 & 7)];
#pragma unroll
            for (int r = 0; r < 4; ++r) {
                int gm = gmb + r;
                float v = acc[rt][t][r];
                if (gm < M) C[(size_t)gm * 64 + t * 16 + m16] = __float2half(v);
                float sv = v * ws, dv = v * wd;
                sv += __shfl_xor(sv, 1, 64); dv += __shfl_xor(dv, 1, 64);
                sv += __shfl_xor(sv, 2, 64); dv += __shfl_xor(dv, 2, 64);
                sv += __shfl_xor(sv, 4, 64); dv += __shfl_xor(dv, 4, 64);
                if ((m16 & 7) == 0 && gm < M) {
                    os[gm * 8 + 2 * t + head] = sv;
                    od[gm * 8 + 2 * t + head] = dv;
                }
            }
        }
    }
}

// ---------------- GEMM2 (MFMA f16, fp32 acc): h2 = h1o @ W2, fused alpha2 + fp8 pack
// NT=8 tiles cover Nc=128; tile t == head t. Epilogue: h2f8 (e4m3 pairs) store +
// as2/ad2 from fp32 acc (reduce over all 16 m16 lanes).

__global__ __launch_bounds__(256) void gemm2_k(const _Float16* __restrict__ A,
                                               const _Float16* __restrict__ BT,
                                               const float* __restrict__ a_s,
                                               const float* __restrict__ a_d,
                                               unsigned short* __restrict__ Cf8,
                                               float* __restrict__ os,
                                               float* __restrict__ od, int M) {
    constexpr int NT = 8, K = 64;
    int wave = threadIdx.x >> 6, lane = threadIdx.x & 63;
    int m16 = lane & 15, quad = lane >> 4;
    int arow = blockIdx.x * 64 + wave * 16 + m16;
    int arc = arow < M ? arow : M - 1;
    floatx4 acc[NT] = {};
    for (int k0 = 0; k0 < K; k0 += 32) {
        half8 af = *(const half8*)(A + (size_t)arc * K + k0 + quad * 8);
#pragma unroll
        for (int t = 0; t < NT; ++t) {
            half8 bf = *(const half8*)(BT + (size_t)(t * 16 + m16) * K + k0 + quad * 8);
            acc[t] = __builtin_amdgcn_mfma_f32_16x16x32_f16(af, bf, acc[t], 0, 0, 0);
        }
    }
    int gm0 = blockIdx.x * 64 + wave * 16 + quad * 4;
#pragma unroll
    for (int t = 0; t < NT; ++t) {
        float ws = a_s[t * 16 + m16];
        float wd = a_d[t * 16 + m16];
#pragma unroll
        for (int r = 0; r < 4; ++r) {
            int gm = gm0 + r;
            float v = acc[t][r];
            float o = __shfl_xor(v, 1, 64);  // neighboring column
            if (gm < M && !(m16 & 1)) {
                unsigned p = __builtin_amdgcn_cvt_pk_fp8_f32(v, o, 0, false);
                Cf8[(size_t)gm * 64 + t * 8 + (m16 >> 1)] = (unsigned short)(p & 0xffff);
            }
            float s = v * ws, d = v * wd;
            s += __shfl_xor(s, 1, 64); d += __shfl_xor(d, 1, 64);
            s += __shfl_xor(s, 2, 64); d += __shfl_xor(d, 2, 64);
            s += __shfl_xor(s, 4, 64); d += __shfl_xor(d, 4, 64);
            s += __shfl_xor(s, 8, 64); d += __shfl_xor(d, 8, 64);
            if (gm < M && m16 == t) {
                os[gm * 8 + t] = s;
                od[gm * 8 + t] = d;
            }
        }
    }
}

// ---------------- layer 1 aggregation: shuffle-free, 8B/lane gathers ---------------
// 256-thread block = 4 waves = 8 nodes. Per wave: 2 nodes (one per 32-lane half).
// Within a half: 2 edge-groups of 16 lanes (jj = ll>>4); lane k = ll&15 covers f16
// channels 4k..4k+3 (uint2 gather), head = k>>1. 16-edge main batch: 8 csr loads ->
// 8 as loads -> 8 gathers, phase-separated for MLP. No per-edge cross-lane shuffles.

__global__ __launch_bounds__(256) void aggregate1_k(
    const uint2* __restrict__ H1, const float* __restrict__ as,
    const float* __restrict__ ad, const int* __restrict__ row_start,
    const int* __restrict__ csr, const float* __restrict__ b1,
    uint2* __restrict__ h1o, int N) {
    int l = threadIdx.x & 63;
    int wv = threadIdx.x >> 6;
    int ll = l & 31;
    int n = min((int)(blockIdx.x * 8 + wv * 2 + (l >> 5)), N - 1);
    int k = ll & 15;   // uint2 index within 128B row
    int jj = ll >> 4;  // edge-group 0/1
    int h = k >> 1;    // head

    float adv = ad[n * 8 + h];
    float e0 = as[n * 8 + h] + adv;
    e0 = fmaxf(e0, NEG_SLOPE * e0);
    float ex0 = __expf(e0);
    float x0 = jj ? 0.f : ex0;  // self loop counted once (group 0 only)

    uint2 sv = H1[(size_t)n * 16 + k];
    float2 s01 = __half22float2(*(const __half2*)&sv.x);
    float2 s23 = __half22float2(*(const __half2*)&sv.y);
    float denom = x0;
    float a0 = x0 * s01.x, a1 = x0 * s01.y, a2 = x0 * s23.x, a3 = x0 * s23.y;

    int e = row_start[n], end = row_start[n + 1];
    for (; e + 16 <= end; e += 16) {  // 16-edge batch: deep MLP
        int sj[8];
        float xv[8];
#pragma unroll
        for (int u = 0; u < 8; ++u) sj[u] = csr[e + 2 * u + jj];
#pragma unroll
        for (int u = 0; u < 8; ++u) {
            float t = as[sj[u] * 8 + h] + adv;
            t = fmaxf(t, NEG_SLOPE * t);
            xv[u] = __expf(t);
        }
#pragma unroll
        for (int u = 0; u < 8; ++u) {
            uint2 gv = H1[(size_t)sj[u] * 16 + k];
            float2 v01 = __half22float2(*(const __half2*)&gv.x);
            float2 v23 = __half22float2(*(const __half2*)&gv.y);
            denom += xv[u];
            a0 = fmaf(xv[u], v01.x, a0); a1 = fmaf(xv[u], v01.y, a1);
            a2 = fmaf(xv[u], v23.x, a2); a3 = fmaf(xv[u], v23.y, a3);
        }
    }
    for (; e + 8 <= end; e += 8) {
#pragma unroll
        for (int u = 0; u < 4; ++u) {
            int sj = csr[e + 2 * u + jj];
            float t = as[sj * 8 + h] + adv;
            t = fmaxf(t, NEG_SLOPE * t);
            float x = __expf(t);
            uint2 gv = H1[(size_t)sj * 16 + k];
            float2 v01 = __half22float2(*(const __half2*)&gv.x);
            float2 v23 = __half22float2(*(const __half2*)&gv.y);
            denom += x;
            a0 = fmaf(x, v01.x, a0); a1 = fmaf(x, v01.y, a1);
            a2 = fmaf(x, v23.x, a2); a3 = fmaf(x, v23.y, a3);
        }
    }
    if (e < end) {  // predicated tail: covers up to 7 remaining edges
#pragma unroll
        for (int u = 0; u < 4; ++u) {
            int idx = e + 2 * u + jj;
            int sj = csr[min(idx, end - 1)];
            float t = as[sj * 8 + h] + adv;
            t = fmaxf(t, NEG_SLOPE * t);
            float x = idx < end ? __expf(t) : 0.f;
            uint2 gv = H1[(size_t)sj * 16 + k];
            float2 v01 = __half22float2(*(const __half2*)&gv.x);
            float2 v23 = __half22float2(*(const __half2*)&gv.y);
            denom += x;
            a0 = fmaf(x, v01.x, a0); a1 = fmaf(x, v01.y, a1);
            a2 = fmaf(x, v23.x, a2); a3 = fmaf(x, v23.y, a3);
        }
    }
    // combine the two edge-groups
    denom += __shfl_xor(denom, 16, 64);
    a0 += __shfl_xor(a0, 16, 64);
    a1 += __shfl_xor(a1, 16, 64);
    a2 += __shfl_xor(a2, 16, 64);
    a3 += __shfl_xor(a3, 16, 64);
    float inv = 1.f / denom;
    float r0 = a0 * inv + b1[4 * k + 0];
    float r1 = a1 * inv + b1[4 * k + 1];
    float r2 = a2 * inv + b1[4 * k + 2];
    float r3 = a3 * inv + b1[4 * k + 3];
    r0 = r0 > 0.f ? r0 : expm1f(r0);
    r1 = r1 > 0.f ? r1 : expm1f(r1);
    r2 = r2 > 0.f ? r2 : expm1f(r2);
    r3 = r3 > 0.f ? r3 : expm1f(r3);
    if (!jj) {
        __half2 p01 = __floats2half2_rn(r0, r1);
        __half2 p23 = __floats2half2_rn(r2, r3);
        uint2 o;
        o.x = *(const unsigned*)&p01;
        o.y = *(const unsigned*)&p23;
        h1o[(size_t)n * 16 + k] = o;
    }
}

// ---------------- layer 2 aggregation: shuffle-free, 8B/lane fp8 gathers -----------
// Lane k covers byte-channels 8k..8k+7 of the 128 B fp8 row; head = k>>1.
// Same group structure + 16-edge main batch as aggregate1_k; epilogue adds head-mean.

__global__ __launch_bounds__(256) void aggregate2_k(
    const uint2* __restrict__ H2, const float* __restrict__ as,
    const float* __restrict__ ad, const int* __restrict__ row_start,
    const int* __restrict__ csr, const float* __restrict__ b2,
    float* __restrict__ out, int N) {
    int l = threadIdx.x & 63;
    int wv = threadIdx.x >> 6;
    int ll = l & 31;
    int n = min((int)(blockIdx.x * 8 + wv * 2 + (l >> 5)), N - 1);
    int k = ll & 15;
    int jj = ll >> 4;
    int h = k >> 1;

    float adv = ad[n * 8 + h];
    float e0 = as[n * 8 + h] + adv;
    e0 = fmaxf(e0, NEG_SLOPE * e0);
    float ex0 = __expf(e0);
    float x0 = jj ? 0.f : ex0;

    uint2 sv = H2[(size_t)n * 16 + k];
    floatx2 p01 = __builtin_amdgcn_cvt_pk_f32_fp8((int)sv.x, false);
    floatx2 p23 = __builtin_amdgcn_cvt_pk_f32_fp8((int)sv.x, true);
    floatx2 p45 = __builtin_amdgcn_cvt_pk_f32_fp8((int)sv.y, false);
    floatx2 p67 = __builtin_amdgcn_cvt_pk_f32_fp8((int)sv.y, true);
    float denom = x0;
    float a0 = x0 * p01[0], a1 = x0 * p01[1], a2 = x0 * p23[0], a3 = x0 * p23[1];
    float a4 = x0 * p45[0], a5 = x0 * p45[1], a6 = x0 * p67[0], a7 = x0 * p67[1];

    int e = row_start[n], end = row_start[n + 1];
    for (; e + 16 <= end; e += 16) {  // 16-edge batch: deep MLP
        int sj[8];
        float xv[8];
#pragma unroll
        for (int u = 0; u < 8; ++u) sj[u] = csr[e + 2 * u + jj];
#pragma unroll
        for (int u = 0; u < 8; ++u) {
            float t = as[sj[u] * 8 + h] + adv;
            t = fmaxf(t, NEG_SLOPE * t);
            xv[u] = __expf(t);
        }
#pragma unroll
        for (int u = 0; u < 8; ++u) {
            uint2 gv = H2[(size_t)sj[u] * 16 + k];
            floatx2 v01 = __builtin_amdgcn_cvt_pk_f32_fp8((int)gv.x, false);
            floatx2 v23 = __builtin_amdgcn_cvt_pk_f32_fp8((int)gv.x, true);
            floatx2 v45 = __builtin_amdgcn_cvt_pk_f32_fp8((int)gv.y, false);
            floatx2 v67 = __builtin_amdgcn_cvt_pk_f32_fp8((int)gv.y, true);
            float x = xv[u];
            denom += x;
            a0 = fmaf(x, v01[0], a0); a1 = fmaf(x, v01[1], a1);
            a2 = fmaf(x, v23[0], a2); a3 = fmaf(x, v23[1], a3);
            a4 = fmaf(x, v45[0], a4); a5 = fmaf(x, v45[1], a5);
            a6 = fmaf(x, v67[0], a6); a7 = fmaf(x, v67[1], a7);
        }
    }
    for (; e + 8 <= end; e += 8) {
#pragma unroll
        for (int u = 0; u < 4; ++u) {
            int sj = csr[e + 2 * u + jj];
            float t = as[sj * 8 + h] + adv;
            t = fmaxf(t, NEG_SLOPE * t);
            float x = __expf(t);
            uint2 gv = H2[(size_t)sj * 16 + k];
            floatx2 v01 = __builtin_amdgcn_cvt_pk_f32_fp8((int)gv.x, false);
            floatx2 v23 = __builtin_amdgcn_cvt_pk_f32_fp8((int)gv.x, true);
            floatx2 v45 = __builtin_amdgcn_cvt_pk_f32_fp8((int)gv.y, false);
            floatx2 v67 = __builtin_amdgcn_cvt_pk_f32_fp8((int)gv.y, true);
            denom += x;
            a0 = fmaf(x, v01[0], a0); a1 = fmaf(x, v01[1], a1);
            a2 = fmaf(x, v23[0], a2); a3 = fmaf(x, v23[1], a3);
            a4 = fmaf(x, v45[0], a4); a5 = fmaf(x, v45[1], a5);
            a6 = fmaf(x, v67[0], a6); a7 = fmaf(x, v67[1], a7);
        }
    }
    if (e < end) {  // predicated tail
#pragma unroll
        for (int u = 0; u < 4; ++u) {
            int idx = e + 2 * u + jj;
            int sj = csr[min(idx, end - 1)];
            float t = as[sj * 8 + h] + adv;
            t = fmaxf(t, NEG_SLOPE * t);
            float x = idx < end ? __expf(t) : 0.f;
            uint2 gv = H2[(size_t)sj * 16 + k];
            floatx2 v01 = __builtin_amdgcn_cvt_pk_f32_fp8((int)gv.x, false);
            floatx2 v23 = __builtin_amdgcn_cvt_pk_f32_fp8((int)gv.x, true);
            floatx2 v45 = __builtin_amdgcn_cvt_pk_f32_fp8((int)gv.y, false);
            floatx2 v67 = __builtin_amdgcn_cvt_pk_f32_fp8((int)gv.y, true);
            denom += x;
            a0 = fmaf(x, v01[0], a0); a1 = fmaf(x, v01[1], a1);
            a2 = fmaf(x, v23[0], a2); a3 = fmaf(x, v23[1], a3);
            a4 = fmaf(x, v45[0], a4); a5 = fmaf(x, v45[1], a5);
            a6 = fmaf(x, v67[0], a6); a7 = fmaf(x, v67[1], a7);
        }
    }
    // group-combine denom, normalize per-group partials, then sum groups+heads
    denom += __shfl_xor(denom, 16, 64);
    float inv = 1.f / denom;
    a0 *= inv; a1 *= inv; a2 *= inv; a3 *= inv;
    a4 *= inv; a5 *= inv; a6 *= inv; a7 *= inv;
#pragma unroll
    for (int m = 2; m <= 16; m <<= 1) {  // k bits 1..3 (heads) + bit 4 (groups)
        a0 += __shfl_xor(a0, m, 64);
        a1 += __shfl_xor(a1, m, 64);
        a2 += __shfl_xor(a2, m, 64);
        a3 += __shfl_xor(a3, m, 64);
        a4 += __shfl_xor(a4, m, 64);
        a5 += __shfl_xor(a5, m, 64);
        a6 += __shfl_xor(a6, m, 64);
        a7 += __shfl_xor(a7, m, 64);
    }
    if (ll < 2) {  // lane k=0 -> channels 0..7, k=1 -> channels 8..15
        int c0 = k * 8;
        float4 o0, o1;
        o0.x = a0 * 0.125f + b2[c0 + 0];
        o0.y = a1 * 0.125f + b2[c0 + 1];
        o0.z = a2 * 0.125f + b2[c0 + 2];
        o0.w = a3 * 0.125f + b2[c0 + 3];
        o1.x = a4 * 0.125f + b2[c0 + 4];
        o1.y = a5 * 0.125f + b2[c0 + 5];
        o1.z = a6 * 0.125f + b2[c0 + 6];
        o1.w = a7 * 0.125f + b2[c0 + 7];
        *(float4*)(out + (size_t)n * 16 + c0) = o0;
        *(float4*)(out + (size_t)n * 16 + c0 + 4) = o1;
    }
}

// ---------------- launch ----------------

extern "C" void kernel_launch(void* const* d_in, const int* in_sizes, int n_in,
                              void* d_out, int out_size, void* d_ws, size_t ws_size,
                              hipStream_t stream) {
    (void)n_in; (void)out_size; (void)ws_size;
    const float* x      = (const float*)d_in[0];
    const int*   ei     = (const int*)d_in[1];
    const float* W1     = (const float*)d_in[2];
    const float* a_src1 = (const float*)d_in[3];
    const float* a_dst1 = (const float*)d_in[4];
    const float* b1     = (const float*)d_in[5];
    const float* W2     = (const float*)d_in[6];
    const float* a_src2 = (const float*)d_in[7];
    const float* a_dst2 = (const float*)d_in[8];
    const float* b2     = (const float*)d_in[9];

    int N = in_sizes[0] / 512;
    int E = in_sizes[1] / 2;
    const int* src = ei;
    const int* dst = ei + E;
    int NB = (N + 511) >> 9;  // 196 for N=100000; LDS arrays assume <= 256

    char* ws = (char*)d_ws;
    size_t off = 0;
    auto alloc = [&](size_t bytes) -> void* {
        void* p = ws + off;
        off = (off + bytes + 255) & ~(size_t)255;
        return p;
    };
    __half* h1  = (__half*)alloc((size_t)N * 64 * 2);
    __half* h1o = (__half*)alloc((size_t)N * 64 * 2);
    unsigned short* h2f8 = (unsigned short*)alloc((size_t)N * 64 * 2);  // fp8 pairs
    float* as1  = (float*)alloc((size_t)N * 8 * 4);
    float* ad1  = (float*)alloc((size_t)N * 8 * 4);
    float* as2  = (float*)alloc((size_t)N * 8 * 4);
    float* ad2  = (float*)alloc((size_t)N * 8 * 4);
    _Float16* W1T = (_Float16*)alloc((size_t)512 * 64 * 2);
    _Float16* W2T = (_Float16*)alloc((size_t)64 * 128 * 2);
    int* row_start = (int*)alloc((size_t)(N + 1) * 4);
    int* bhist     = (int*)alloc(256 * 4);
    int* bbase     = (int*)alloc(257 * 4);
    int* bh_blocks = (int*)alloc((size_t)512 * 256 * 4);
    int* pbase     = (int*)alloc((size_t)512 * 256 * 4);
    unsigned int* part = (unsigned int*)alloc((size_t)E * 4);
    int* csr       = (int*)alloc((size_t)E * 4);

    // --- CSR build chain (one edge pass each for hist and partition) ---
    hipMemsetAsync(bhist, 0, 256 * 4, stream);
    pre_k<<<672, 256, 0, stream>>>(dst, E, bhist, bh_blocks, NB, W1, W1T, W2, W2T);
    bucket_scan_k<<<1, 256, 0, stream>>>(bhist, NB, bbase, row_start, N, E);
    colscan_k<<<NB, 256, 0, stream>>>(bh_blocks, bbase, pbase);
    partition_k<<<512, 256, 0, stream>>>(src, dst, E, pbase, part);
    bucket_build_k<<<NB, 512, 0, stream>>>(part, bbase, row_start, csr, N);

    int g1blocks = (N + 127) / 128;
    int g2blocks = (N + 63) / 64;
    int ablocks  = (N + 7) / 8;

    // --- layer 1 ---
    gemm1_k<<<g1blocks, 256, 0, stream>>>(x, W1T, a_src1, a_dst1, h1, as1, ad1, N);
    aggregate1_k<<<ablocks, 256, 0, stream>>>((const uint2*)h1, as1, ad1, row_start,
                                              csr, b1, (uint2*)h1o, N);

    // --- layer 2 ---
    gemm2_k<<<g2blocks, 256, 0, stream>>>((const _Float16*)h1o, W2T, a_src2, a_dst2,
                                          h2f8, as2, ad2, N);
    aggregate2_k<<<ablocks, 256, 0, stream>>>((const uint2*)h2f8, as2, ad2,
                                              row_start, csr, b2, (float*)d_out, N);
}

// Round 4
// 610.378 us; speedup vs baseline: 1.0677x; 1.0270x over previous
//
#include <hip/hip_runtime.h>
#include <hip/hip_bf16.h>
#include <hip/hip_fp16.h>
#include <cstddef>

#define NEG_SLOPE 0.2f

typedef _Float16 half8 __attribute__((ext_vector_type(8)));
typedef __fp16 fp16x2 __attribute__((ext_vector_type(2)));
typedef float floatx4 __attribute__((ext_vector_type(4)));
typedef float floatx2 __attribute__((ext_vector_type(2)));

union H8 { half8 v; fp16x2 p[4]; };

// ================= bucketed CSR build =================
// Bucket = 512 consecutive dst nodes. NB = ceil(N/512) (== 196 for N=100000, <= 256).
// part[] holds (src << 9) | (dst & 511) per edge, grouped by bucket.
// pre_k saves per-block histograms; scan2_k computes bucket bases (block 0) and
// per-(block,bucket) LOCAL offsets (blocks 1..NB) in one dispatch; partition adds them.

// ---- fused: bucket histogram (blocks 0..511) + W1 transpose (512..639) + W2 transpose (640..671)
__global__ __launch_bounds__(256) void pre_k(const int* __restrict__ dst, int E,
                                             int* __restrict__ bhist, int* __restrict__ bh_blocks,
                                             int NB,
                                             const float* __restrict__ W1, _Float16* __restrict__ W1T,
                                             const float* __restrict__ W2, _Float16* __restrict__ W2T) {
    int b = blockIdx.x;
    if (b < 512) {
        __shared__ int lh[256];
        for (int t = threadIdx.x; t < 256; t += 256) lh[t] = 0;
        __syncthreads();
        int per = (E + 511) / 512;
        int s = b * per;
        int e = min(s + per, E);
        for (int i = s + threadIdx.x; i < e; i += 256) atomicAdd(&lh[dst[i] >> 9], 1);
        __syncthreads();
        for (int t = threadIdx.x; t < 256; t += 256) {
            int c = lh[t];
            bh_blocks[b * 256 + t] = c;
            if (c && t < NB) atomicAdd(&bhist[t], c);
        }
    } else if (b < 640) {
        int i = (b - 512) * 256 + threadIdx.x;  // 512*64 = 32768 elems, 128 blocks
        if (i < 512 * 64) {
            int k = i / 64, n = i % 64;
            W1T[(size_t)n * 512 + k] = (_Float16)W1[i];
        }
    } else {
        int i = (b - 640) * 256 + threadIdx.x;  // 64*128 = 8192 elems, 32 blocks
        if (i < 64 * 128) {
            int k = i / 128, n = i % 128;
            W2T[(size_t)n * 64 + k] = (_Float16)W2[i];
        }
    }
}

// Block 0: exclusive scan of bucket totals -> bbase. Blocks 1..NB: per-bucket scan of
// the 512 per-block counts -> LOCAL write offsets (no bbase dependency).
__global__ __launch_bounds__(256) void scan2_k(const int* __restrict__ bhist, int NB,
                                               const int* __restrict__ bh_blocks,
                                               int* __restrict__ bbase, int* __restrict__ row_start,
                                               int* __restrict__ pbase, int N, int E) {
    __shared__ int tmp[256];
    int tid = threadIdx.x;
    if (blockIdx.x == 0) {
        int v = (tid < NB) ? bhist[tid] : 0;
        tmp[tid] = v;
        __syncthreads();
        for (int d = 1; d < 256; d <<= 1) {
            int t = tmp[tid];
            int a = (tid >= d) ? tmp[tid - d] : 0;
            __syncthreads();
            tmp[tid] = t + a;
            __syncthreads();
        }
        if (tid < NB) bbase[tid] = tmp[tid] - v;  // exclusive
        if (tid == 0) {
            bbase[NB] = E;
            row_start[N] = E;
        }
    } else {
        int t = blockIdx.x - 1;  // bucket
        int v0 = bh_blocks[(2 * tid) * 256 + t];
        int v1 = bh_blocks[(2 * tid + 1) * 256 + t];
        int s = v0 + v1;
        tmp[tid] = s;
        __syncthreads();
        for (int d = 1; d < 256; d <<= 1) {
            int x = tmp[tid];
            int a = (tid >= d) ? tmp[tid - d] : 0;
            __syncthreads();
            tmp[tid] = x + a;
            __syncthreads();
        }
        int excl = tmp[tid] - s;  // local (bucket-relative) offset
        pbase[(2 * tid) * 256 + t] = excl;
        pbase[(2 * tid + 1) * 256 + t] = excl + v0;
    }
}

// One workgroup per bucket: per-node counts + scan in LDS -> row_start; then scatter
// src ids into the bucket's contiguous csr window (L2-resident, ~64 KB).
__global__ __launch_bounds__(512) void bucket_build_k(const unsigned int* __restrict__ part,
                                                      const int* __restrict__ bbase,
                                                      int* __restrict__ row_start,
                                                      int* __restrict__ csr, int N) {
    __shared__ int cnt[512];
    __shared__ int cur[512];
    int b = blockIdx.x, tid = threadIdx.x;
    int n0 = b << 9;
    int s = bbase[b], e2 = bbase[b + 1];
    cnt[tid] = 0;
    __syncthreads();
    for (int i = s + tid; i < e2; i += 512) atomicAdd(&cnt[part[i] & 511], 1);
    __syncthreads();
    int v = cnt[tid];
    for (int d = 1; d < 512; d <<= 1) {  // inclusive scan, in place
        int t = cnt[tid];
        int a = (tid >= d) ? cnt[tid - d] : 0;
        __syncthreads();
        cnt[tid] = t + a;
        __syncthreads();
    }
    int excl = cnt[tid] - v;
    if (n0 + tid < N) row_start[n0 + tid] = s + excl;
    cur[tid] = excl;
    __syncthreads();
    for (int i = s + tid; i < e2; i += 512) {
        unsigned u = part[i];
        int p = atomicAdd(&cur[u & 511], 1);
        csr[s + p] = (int)(u >> 9);
    }
}

// ---------------- fused partition + GEMM1 -------------------------------------------
// Blocks 0..511: single-pass partition (bases precomputed, LDS-local cursors only).
// Blocks 512..: GEMM1 h1 = x @ W1 (f16 MFMA, fp32 acc), 128 rows/block, K-step 64,
// W1T K-slice in XOR-swizzled double-buffered LDS, A cvt via v_cvt_pkrtz, fused alpha1.
// Independent tasks; partition (~30 us) hides fully under GEMM1.

__global__ __launch_bounds__(256) void part_gemm1_k(
    // gemm1 args
    const float* __restrict__ A, const _Float16* __restrict__ BT,
    const float* __restrict__ a_s, const float* __restrict__ a_d,
    __half* __restrict__ C, float* __restrict__ os, float* __restrict__ od, int M,
    // partition args
    const int* __restrict__ src, const int* __restrict__ dst, int E,
    const int* __restrict__ bbase, const int* __restrict__ pbase,
    unsigned int* __restrict__ part) {
    __shared__ __align__(16) _Float16 Bs[2][64 * 64];  // 16 KB
    __shared__ int lbase[256];
    __shared__ int lh[256];

    if (blockIdx.x < 512) {
        int b = blockIdx.x;
        for (int t = threadIdx.x; t < 256; t += 256) {
            lbase[t] = bbase[t] + pbase[b * 256 + t];
            lh[t] = 0;
        }
        __syncthreads();
        int per = (E + 511) / 512;
        int s = b * per;
        int e = min(s + per, E);
        for (int i = s + threadIdx.x; i < e; i += 256) {
            int d = dst[i];
            int bk = d >> 9;
            int lo = atomicAdd(&lh[bk], 1);
            part[lbase[bk] + lo] = ((unsigned)src[i] << 9) | (unsigned)(d & 511);
        }
        return;
    }

    // ---- GEMM1 body ----
    constexpr int K = 512;
    int bid = blockIdx.x - 512;
    int tid = threadIdx.x;
    int wave = tid >> 6, lane = tid & 63;
    int m16 = lane & 15, quad = lane >> 4;
    int row0 = bid * 128 + wave * 32;
    int r0 = min(row0 + m16, M - 1);
    int r1 = min(row0 + 16 + m16, M - 1);
    const float* a0p = A + (size_t)r0 * K + quad * 8;
    const float* a1p = A + (size_t)r1 * K + quad * 8;

    // B staging: thread -> row brow (0..63), colblock bcb (0..3) = 2x half8 per step.
    int brow = tid >> 2;
    int bcb = tid & 3;
    const _Float16* bsrc = BT + (size_t)brow * K + bcb * 16;
    int du0 = ((bcb * 2 + 0) * 8) ^ ((brow & 7) << 3);  // swizzled half-offsets
    int du1 = ((bcb * 2 + 1) * 8) ^ ((brow & 7) << 3);
    int dbase = brow * 64;

    floatx4 acc[2][4] = {};
    // ---- prologue: load + stage step 0 ----
    half8 b0 = *(const half8*)(bsrc + 0);
    half8 b1 = *(const half8*)(bsrc + 8);
    float4 a00 = *(const float4*)(a0p + 0);
    float4 a01 = *(const float4*)(a0p + 4);
    float4 a02 = *(const float4*)(a0p + 32);
    float4 a03 = *(const float4*)(a0p + 36);
    float4 a10 = *(const float4*)(a1p + 0);
    float4 a11 = *(const float4*)(a1p + 4);
    float4 a12 = *(const float4*)(a1p + 32);
    float4 a13 = *(const float4*)(a1p + 36);
    *(half8*)(&Bs[0][0] + dbase + du0) = b0;
    *(half8*)(&Bs[0][0] + dbase + du1) = b1;
    __syncthreads();

    int cur = 0;
    for (int s = 0; s < 8; ++s) {
        // convert this step's A to f16 fragments (packed rtz cvt: 16 instrs not 32)
        half8 af[2][2];
        H8 u;
        u.p[0] = __builtin_amdgcn_cvt_pkrtz(a00.x, a00.y);
        u.p[1] = __builtin_amdgcn_cvt_pkrtz(a00.z, a00.w);
        u.p[2] = __builtin_amdgcn_cvt_pkrtz(a01.x, a01.y);
        u.p[3] = __builtin_amdgcn_cvt_pkrtz(a01.z, a01.w);
        af[0][0] = u.v;
        u.p[0] = __builtin_amdgcn_cvt_pkrtz(a02.x, a02.y);
        u.p[1] = __builtin_amdgcn_cvt_pkrtz(a02.z, a02.w);
        u.p[2] = __builtin_amdgcn_cvt_pkrtz(a03.x, a03.y);
        u.p[3] = __builtin_amdgcn_cvt_pkrtz(a03.z, a03.w);
        af[0][1] = u.v;
        u.p[0] = __builtin_amdgcn_cvt_pkrtz(a10.x, a10.y);
        u.p[1] = __builtin_amdgcn_cvt_pkrtz(a10.z, a10.w);
        u.p[2] = __builtin_amdgcn_cvt_pkrtz(a11.x, a11.y);
        u.p[3] = __builtin_amdgcn_cvt_pkrtz(a11.z, a11.w);
        af[1][0] = u.v;
        u.p[0] = __builtin_amdgcn_cvt_pkrtz(a12.x, a12.y);
        u.p[1] = __builtin_amdgcn_cvt_pkrtz(a12.z, a12.w);
        u.p[2] = __builtin_amdgcn_cvt_pkrtz(a13.x, a13.y);
        u.p[3] = __builtin_amdgcn_cvt_pkrtz(a13.z, a13.w);
        af[1][1] = u.v;
        if (s < 7) {  // issue next step's loads early; they fly under the MFMAs
            int k1 = (s + 1) * 64;
            b0 = *(const half8*)(bsrc + k1);
            b1 = *(const half8*)(bsrc + k1 + 8);
            a00 = *(const float4*)(a0p + k1);
            a01 = *(const float4*)(a0p + k1 + 4);
            a02 = *(const float4*)(a0p + k1 + 32);
            a03 = *(const float4*)(a0p + k1 + 36);
            a10 = *(const float4*)(a1p + k1);
            a11 = *(const float4*)(a1p + k1 + 4);
            a12 = *(const float4*)(a1p + k1 + 32);
            a13 = *(const float4*)(a1p + k1 + 36);
        }
        const _Float16* bsC = &Bs[cur][0];
#pragma unroll
        for (int t = 0; t < 4; ++t) {
#pragma unroll
            for (int kk = 0; kk < 2; ++kk) {
                int idx = (t * 16 + m16) * 64 + ((kk * 32 + quad * 8) ^ ((m16 & 7) << 3));
                half8 bf = *(const half8*)(bsC + idx);
                acc[0][t] = __builtin_amdgcn_mfma_f32_16x16x32_f16(af[0][kk], bf, acc[0][t], 0, 0, 0);
                acc[1][t] = __builtin_amdgcn_mfma_f32_16x16x32_f16(af[1][kk], bf, acc[1][t], 0, 0, 0);
            }
        }
        if (s < 7) {  // write-late staging of step s+1 into the other buffer
            _Float16* bsN = &Bs[cur ^ 1][0];
            *(half8*)(bsN + dbase + du0) = b0;
            *(half8*)(bsN + dbase + du1) = b1;
        }
        __syncthreads();
        cur ^= 1;
    }

    // ---- epilogue: C store + fused alpha1 ----
    int head = (m16 >> 3);  // + 2t below
#pragma unroll
    for (int rt = 0; rt < 2; ++rt) {
        int gmb = row0 + rt * 16 + quad * 4;
#pragma unroll
        for (int t = 0; t < 4; ++t) {
            float ws = a_s[(2 * t + head) * 8 + (m16 & 7)];
            float wd = a_d[(2 * t + head) * 8 + (m16 & 7)];
#pragma unroll
            for (int r = 0; r < 4; ++r) {
                int gm = gmb + r;
                float v = acc[rt][t][r];
                if (gm < M) C[(size_t)gm * 64 + t * 16 + m16] = __float2half(v);
                float sv = v * ws, dv = v * wd;
                sv += __shfl_xor(sv, 1, 64); dv += __shfl_xor(dv, 1, 64);
                sv += __shfl_xor(sv, 2, 64); dv += __shfl_xor(dv, 2, 64);
                sv += __shfl_xor(sv, 4, 64); dv += __shfl_xor(dv, 4, 64);
                if ((m16 & 7) == 0 && gm < M) {
                    os[gm * 8 + 2 * t + head] = sv;
                    od[gm * 8 + 2 * t + head] = dv;
                }
            }
        }
    }
}

// ---------------- GEMM2 (MFMA f16, fp32 acc): h2 = h1o @ W2, fused alpha2 + fp8 pack
// NT=8 tiles cover Nc=128; tile t == head t. Epilogue: h2f8 (e4m3 pairs) store +
// as2/ad2 from fp32 acc (reduce over all 16 m16 lanes).

__global__ __launch_bounds__(256) void gemm2_k(const _Float16* __restrict__ A,
                                               const _Float16* __restrict__ BT,
                                               const float* __restrict__ a_s,
                                               const float* __restrict__ a_d,
                                               unsigned short* __restrict__ Cf8,
                                               float* __restrict__ os,
                                               float* __restrict__ od, int M) {
    constexpr int NT = 8, K = 64;
    int wave = threadIdx.x >> 6, lane = threadIdx.x & 63;
    int m16 = lane & 15, quad = lane >> 4;
    int arow = blockIdx.x * 64 + wave * 16 + m16;
    int arc = arow < M ? arow : M - 1;
    floatx4 acc[NT] = {};
    for (int k0 = 0; k0 < K; k0 += 32) {
        half8 af = *(const half8*)(A + (size_t)arc * K + k0 + quad * 8);
#pragma unroll
        for (int t = 0; t < NT; ++t) {
            half8 bf = *(const half8*)(BT + (size_t)(t * 16 + m16) * K + k0 + quad * 8);
            acc[t] = __builtin_amdgcn_mfma_f32_16x16x32_f16(af, bf, acc[t], 0, 0, 0);
        }
    }
    int gm0 = blockIdx.x * 64 + wave * 16 + quad * 4;
#pragma unroll
    for (int t = 0; t < NT; ++t) {
        float ws = a_s[t * 16 + m16];
        float wd = a_d[t * 16 + m16];
#pragma unroll
        for (int r = 0; r < 4; ++r) {
            int gm = gm0 + r;
            float v = acc[t][r];
            float o = __shfl_xor(v, 1, 64);  // neighboring column
            if (gm < M && !(m16 & 1)) {
                unsigned p = __builtin_amdgcn_cvt_pk_fp8_f32(v, o, 0, false);
                Cf8[(size_t)gm * 64 + t * 8 + (m16 >> 1)] = (unsigned short)(p & 0xffff);
            }
            float s = v * ws, d = v * wd;
            s += __shfl_xor(s, 1, 64); d += __shfl_xor(d, 1, 64);
            s += __shfl_xor(s, 2, 64); d += __shfl_xor(d, 2, 64);
            s += __shfl_xor(s, 4, 64); d += __shfl_xor(d, 4, 64);
            s += __shfl_xor(s, 8, 64); d += __shfl_xor(d, 8, 64);
            if (gm < M && m16 == t) {
                os[gm * 8 + t] = s;
                od[gm * 8 + t] = d;
            }
        }
    }
}

// ---------------- layer 1 aggregation: shuffle-free, software-pipelined ------------
// 256-thread block = 4 waves = 8 nodes; 32-lane half per node; 2 edge-groups of 16
// lanes (jj); lane k covers f16 channels 4k..4k+3 (uint2), head = k>>1.
// Main loop pipelined across 16-edge batches: issue order = as(A), csr(A+1),
// gather(A) -> waiting for `as` leaves gathers + next-csr in flight (~1 round-trip
// per batch instead of 3).

__global__ __launch_bounds__(256) void aggregate1_k(
    const uint2* __restrict__ H1, const float* __restrict__ as,
    const float* __restrict__ ad, const int* __restrict__ row_start,
    const int* __restrict__ csr, const float* __restrict__ b1,
    uint2* __restrict__ h1o, int N) {
    int l = threadIdx.x & 63;
    int wv = threadIdx.x >> 6;
    int ll = l & 31;
    int n = min((int)(blockIdx.x * 8 + wv * 2 + (l >> 5)), N - 1);
    int k = ll & 15;   // uint2 index within 128B row
    int jj = ll >> 4;  // edge-group 0/1
    int h = k >> 1;    // head

    int e = row_start[n], end = row_start[n + 1];
    int sjA[8];
    if (e + 16 <= end) {
#pragma unroll
        for (int u = 0; u < 8; ++u) sjA[u] = csr[e + 2 * u + jj];
    }

    float adv = ad[n * 8 + h];
    float e0 = as[n * 8 + h] + adv;
    e0 = fmaxf(e0, NEG_SLOPE * e0);
    float ex0 = __expf(e0);
    float x0 = jj ? 0.f : ex0;  // self loop counted once (group 0 only)

    uint2 sv = H1[(size_t)n * 16 + k];
    float2 s01 = __half22float2(*(const __half2*)&sv.x);
    float2 s23 = __half22float2(*(const __half2*)&sv.y);
    float denom = x0;
    float a0 = x0 * s01.x, a1 = x0 * s01.y, a2 = x0 * s23.x, a3 = x0 * s23.y;

    for (; e + 16 <= end; e += 16) {
        bool hasNext = (e + 32 <= end);
        float tA[8];
        int sjN[8];
        uint2 gv[8];
#pragma unroll
        for (int u = 0; u < 8; ++u) tA[u] = as[sjA[u] * 8 + h];
#pragma unroll
        for (int u = 0; u < 8; ++u) sjN[u] = hasNext ? csr[e + 16 + 2 * u + jj] : sjA[u];
#pragma unroll
        for (int u = 0; u < 8; ++u) gv[u] = H1[(size_t)sjA[u] * 16 + k];
        float xv[8];
#pragma unroll
        for (int u = 0; u < 8; ++u) {
            float t = tA[u] + adv;
            t = fmaxf(t, NEG_SLOPE * t);
            xv[u] = __expf(t);
        }
#pragma unroll
        for (int u = 0; u < 8; ++u) {
            float2 v01 = __half22float2(*(const __half2*)&gv[u].x);
            float2 v23 = __half22float2(*(const __half2*)&gv[u].y);
            denom += xv[u];
            a0 = fmaf(xv[u], v01.x, a0); a1 = fmaf(xv[u], v01.y, a1);
            a2 = fmaf(xv[u], v23.x, a2); a3 = fmaf(xv[u], v23.y, a3);
        }
#pragma unroll
        for (int u = 0; u < 8; ++u) sjA[u] = sjN[u];
    }
    for (; e + 8 <= end; e += 8) {
#pragma unroll
        for (int u = 0; u < 4; ++u) {
            int sj = csr[e + 2 * u + jj];
            float t = as[sj * 8 + h] + adv;
            t = fmaxf(t, NEG_SLOPE * t);
            float x = __expf(t);
            uint2 gv = H1[(size_t)sj * 16 + k];
            float2 v01 = __half22float2(*(const __half2*)&gv.x);
            float2 v23 = __half22float2(*(const __half2*)&gv.y);
            denom += x;
            a0 = fmaf(x, v01.x, a0); a1 = fmaf(x, v01.y, a1);
            a2 = fmaf(x, v23.x, a2); a3 = fmaf(x, v23.y, a3);
        }
    }
    if (e < end) {  // predicated tail: covers up to 7 remaining edges
#pragma unroll
        for (int u = 0; u < 4; ++u) {
            int idx = e + 2 * u + jj;
            int sj = csr[min(idx, end - 1)];
            float t = as[sj * 8 + h] + adv;
            t = fmaxf(t, NEG_SLOPE * t);
            float x = idx < end ? __expf(t) : 0.f;
            uint2 gv = H1[(size_t)sj * 16 + k];
            float2 v01 = __half22float2(*(const __half2*)&gv.x);
            float2 v23 = __half22float2(*(const __half2*)&gv.y);
            denom += x;
            a0 = fmaf(x, v01.x, a0); a1 = fmaf(x, v01.y, a1);
            a2 = fmaf(x, v23.x, a2); a3 = fmaf(x, v23.y, a3);
        }
    }
    // combine the two edge-groups
    denom += __shfl_xor(denom, 16, 64);
    a0 += __shfl_xor(a0, 16, 64);
    a1 += __shfl_xor(a1, 16, 64);
    a2 += __shfl_xor(a2, 16, 64);
    a3 += __shfl_xor(a3, 16, 64);
    float inv = 1.f / denom;
    float r0 = a0 * inv + b1[4 * k + 0];
    float r1 = a1 * inv + b1[4 * k + 1];
    float r2 = a2 * inv + b1[4 * k + 2];
    float r3 = a3 * inv + b1[4 * k + 3];
    r0 = r0 > 0.f ? r0 : expm1f(r0);
    r1 = r1 > 0.f ? r1 : expm1f(r1);
    r2 = r2 > 0.f ? r2 : expm1f(r2);
    r3 = r3 > 0.f ? r3 : expm1f(r3);
    if (!jj) {
        __half2 p01 = __floats2half2_rn(r0, r1);
        __half2 p23 = __floats2half2_rn(r2, r3);
        uint2 o;
        o.x = *(const unsigned*)&p01;
        o.y = *(const unsigned*)&p23;
        h1o[(size_t)n * 16 + k] = o;
    }
}

// ---------------- layer 2 aggregation: shuffle-free fp8 gathers, pipelined ---------
// Lane k covers byte-channels 8k..8k+7 of the 128 B fp8 row; head = k>>1.
// Same pipelined main loop as aggregate1_k; epilogue adds head-mean reduction.

__global__ __launch_bounds__(256) void aggregate2_k(
    const uint2* __restrict__ H2, const float* __restrict__ as,
    const float* __restrict__ ad, const int* __restrict__ row_start,
    const int* __restrict__ csr, const float* __restrict__ b2,
    float* __restrict__ out, int N) {
    int l = threadIdx.x & 63;
    int wv = threadIdx.x >> 6;
    int ll = l & 31;
    int n = min((int)(blockIdx.x * 8 + wv * 2 + (l >> 5)), N - 1);
    int k = ll & 15;
    int jj = ll >> 4;
    int h = k >> 1;

    int e = row_start[n], end = row_start[n + 1];
    int sjA[8];
    if (e + 16 <= end) {
#pragma unroll
        for (int u = 0; u < 8; ++u) sjA[u] = csr[e + 2 * u + jj];
    }

    float adv = ad[n * 8 + h];
    float e0 = as[n * 8 + h] + adv;
    e0 = fmaxf(e0, NEG_SLOPE * e0);
    float ex0 = __expf(e0);
    float x0 = jj ? 0.f : ex0;

    uint2 sv = H2[(size_t)n * 16 + k];
    floatx2 p01 = __builtin_amdgcn_cvt_pk_f32_fp8((int)sv.x, false);
    floatx2 p23 = __builtin_amdgcn_cvt_pk_f32_fp8((int)sv.x, true);
    floatx2 p45 = __builtin_amdgcn_cvt_pk_f32_fp8((int)sv.y, false);
    floatx2 p67 = __builtin_amdgcn_cvt_pk_f32_fp8((int)sv.y, true);
    float denom = x0;
    float a0 = x0 * p01[0], a1 = x0 * p01[1], a2 = x0 * p23[0], a3 = x0 * p23[1];
    float a4 = x0 * p45[0], a5 = x0 * p45[1], a6 = x0 * p67[0], a7 = x0 * p67[1];

    for (; e + 16 <= end; e += 16) {
        bool hasNext = (e + 32 <= end);
        float tA[8];
        int sjN[8];
        uint2 gv[8];
#pragma unroll
        for (int u = 0; u < 8; ++u) tA[u] = as[sjA[u] * 8 + h];
#pragma unroll
        for (int u = 0; u < 8; ++u) sjN[u] = hasNext ? csr[e + 16 + 2 * u + jj] : sjA[u];
#pragma unroll
        for (int u = 0; u < 8; ++u) gv[u] = H2[(size_t)sjA[u] * 16 + k];
        float xv[8];
#pragma unroll
        for (int u = 0; u < 8; ++u) {
            float t = tA[u] + adv;
            t = fmaxf(t, NEG_SLOPE * t);
            xv[u] = __expf(t);
        }
#pragma unroll
        for (int u = 0; u < 8; ++u) {
            floatx2 v01 = __builtin_amdgcn_cvt_pk_f32_fp8((int)gv[u].x, false);
            floatx2 v23 = __builtin_amdgcn_cvt_pk_f32_fp8((int)gv[u].x, true);
            floatx2 v45 = __builtin_amdgcn_cvt_pk_f32_fp8((int)gv[u].y, false);
            floatx2 v67 = __builtin_amdgcn_cvt_pk_f32_fp8((int)gv[u].y, true);
            float x = xv[u];
            denom += x;
            a0 = fmaf(x, v01[0], a0); a1 = fmaf(x, v01[1], a1);
            a2 = fmaf(x, v23[0], a2); a3 = fmaf(x, v23[1], a3);
            a4 = fmaf(x, v45[0], a4); a5 = fmaf(x, v45[1], a5);
            a6 = fmaf(x, v67[0], a6); a7 = fmaf(x, v67[1], a7);
        }
#pragma unroll
        for (int u = 0; u < 8; ++u) sjA[u] = sjN[u];
    }
    for (; e + 8 <= end; e += 8) {
#pragma unroll
        for (int u = 0; u < 4; ++u) {
            int sj = csr[e + 2 * u + jj];
            float t = as[sj * 8 + h] + adv;
            t = fmaxf(t, NEG_SLOPE * t);
            float x = __expf(t);
            uint2 gv = H2[(size_t)sj * 16 + k];
            floatx2 v01 = __builtin_amdgcn_cvt_pk_f32_fp8((int)gv.x, false);
            floatx2 v23 = __builtin_amdgcn_cvt_pk_f32_fp8((int)gv.x, true);
            floatx2 v45 = __builtin_amdgcn_cvt_pk_f32_fp8((int)gv.y, false);
            floatx2 v67 = __builtin_amdgcn_cvt_pk_f32_fp8((int)gv.y, true);
            denom += x;
            a0 = fmaf(x, v01[0], a0); a1 = fmaf(x, v01[1], a1);
            a2 = fmaf(x, v23[0], a2); a3 = fmaf(x, v23[1], a3);
            a4 = fmaf(x, v45[0], a4); a5 = fmaf(x, v45[1], a5);
            a6 = fmaf(x, v67[0], a6); a7 = fmaf(x, v67[1], a7);
        }
    }
    if (e < end) {  // predicated tail
#pragma unroll
        for (int u = 0; u < 4; ++u) {
            int idx = e + 2 * u + jj;
            int sj = csr[min(idx, end - 1)];
            float t = as[sj * 8 + h] + adv;
            t = fmaxf(t, NEG_SLOPE * t);
            float x = idx < end ? __expf(t) : 0.f;
            uint2 gv = H2[(size_t)sj * 16 + k];
            floatx2 v01 = __builtin_amdgcn_cvt_pk_f32_fp8((int)gv.x, false);
            floatx2 v23 = __builtin_amdgcn_cvt_pk_f32_fp8((int)gv.x, true);
            floatx2 v45 = __builtin_amdgcn_cvt_pk_f32_fp8((int)gv.y, false);
            floatx2 v67 = __builtin_amdgcn_cvt_pk_f32_fp8((int)gv.y, true);
            denom += x;
            a0 = fmaf(x, v01[0], a0); a1 = fmaf(x, v01[1], a1);
            a2 = fmaf(x, v23[0], a2); a3 = fmaf(x, v23[1], a3);
            a4 = fmaf(x, v45[0], a4); a5 = fmaf(x, v45[1], a5);
            a6 = fmaf(x, v67[0], a6); a7 = fmaf(x, v67[1], a7);
        }
    }
    // group-combine denom, normalize per-group partials, then sum groups+heads
    denom += __shfl_xor(denom, 16, 64);
    float inv = 1.f / denom;
    a0 *= inv; a1 *= inv; a2 *= inv; a3 *= inv;
    a4 *= inv; a5 *= inv; a6 *= inv; a7 *= inv;
#pragma unroll
    for (int m = 2; m <= 16; m <<= 1) {  // k bits 1..3 (heads) + bit 4 (groups)
        a0 += __shfl_xor(a0, m, 64);
        a1 += __shfl_xor(a1, m, 64);
        a2 += __shfl_xor(a2, m, 64);
        a3 += __shfl_xor(a3, m, 64);
        a4 += __shfl_xor(a4, m, 64);
        a5 += __shfl_xor(a5, m, 64);
        a6 += __shfl_xor(a6, m, 64);
        a7 += __shfl_xor(a7, m, 64);
    }
    if (ll < 2) {  // lane k=0 -> channels 0..7, k=1 -> channels 8..15
        int c0 = k * 8;
        float4 o0, o1;
        o0.x = a0 * 0.125f + b2[c0 + 0];
        o0.y = a1 * 0.125f + b2[c0 + 1];
        o0.z = a2 * 0.125f + b2[c0 + 2];
        o0.w = a3 * 0.125f + b2[c0 + 3];
        o1.x = a4 * 0.125f + b2[c0 + 4];
        o1.y = a5 * 0.125f + b2[c0 + 5];
        o1.z = a6 * 0.125f + b2[c0 + 6];
        o1.w = a7 * 0.125f + b2[c0 + 7];
        *(float4*)(out + (size_t)n * 16 + c0) = o0;
        *(float4*)(out + (size_t)n * 16 + c0 + 4) = o1;
    }
}

// ---------------- launch ----------------

extern "C" void kernel_launch(void* const* d_in, const int* in_sizes, int n_in,
                              void* d_out, int out_size, void* d_ws, size_t ws_size,
                              hipStream_t stream) {
    (void)n_in; (void)out_size; (void)ws_size;
    const float* x      = (const float*)d_in[0];
    const int*   ei     = (const int*)d_in[1];
    const float* W1     = (const float*)d_in[2];
    const float* a_src1 = (const float*)d_in[3];
    const float* a_dst1 = (const float*)d_in[4];
    const float* b1     = (const float*)d_in[5];
    const float* W2     = (const float*)d_in[6];
    const float* a_src2 = (const float*)d_in[7];
    const float* a_dst2 = (const float*)d_in[8];
    const float* b2     = (const float*)d_in[9];

    int N = in_sizes[0] / 512;
    int E = in_sizes[1] / 2;
    const int* src = ei;
    const int* dst = ei + E;
    int NB = (N + 511) >> 9;  // 196 for N=100000; LDS arrays assume <= 256

    char* ws = (char*)d_ws;
    size_t off = 0;
    auto alloc = [&](size_t bytes) -> void* {
        void* p = ws + off;
        off = (off + bytes + 255) & ~(size_t)255;
        return p;
    };
    __half* h1  = (__half*)alloc((size_t)N * 64 * 2);
    __half* h1o = (__half*)alloc((size_t)N * 64 * 2);
    unsigned short* h2f8 = (unsigned short*)alloc((size_t)N * 64 * 2);  // fp8 pairs
    float* as1  = (float*)alloc((size_t)N * 8 * 4);
    float* ad1  = (float*)alloc((size_t)N * 8 * 4);
    float* as2  = (float*)alloc((size_t)N * 8 * 4);
    float* ad2  = (float*)alloc((size_t)N * 8 * 4);
    _Float16* W1T = (_Float16*)alloc((size_t)512 * 64 * 2);
    _Float16* W2T = (_Float16*)alloc((size_t)64 * 128 * 2);
    int* row_start = (int*)alloc((size_t)(N + 1) * 4);
    int* bhist     = (int*)alloc(256 * 4);
    int* bbase     = (int*)alloc(257 * 4);
    int* bh_blocks = (int*)alloc((size_t)512 * 256 * 4);
    int* pbase     = (int*)alloc((size_t)512 * 256 * 4);
    unsigned int* part = (unsigned int*)alloc((size_t)E * 4);
    int* csr       = (int*)alloc((size_t)E * 4);

    int g1blocks = (N + 127) / 128;
    int g2blocks = (N + 63) / 64;
    int ablocks  = (N + 7) / 8;

    // --- CSR build chain + layer-1 GEMM (partition hidden under GEMM1) ---
    hipMemsetAsync(bhist, 0, 256 * 4, stream);
    pre_k<<<672, 256, 0, stream>>>(dst, E, bhist, bh_blocks, NB, W1, W1T, W2, W2T);
    scan2_k<<<1 + NB, 256, 0, stream>>>(bhist, NB, bh_blocks, bbase, row_start, pbase, N, E);
    part_gemm1_k<<<512 + g1blocks, 256, 0, stream>>>(x, W1T, a_src1, a_dst1, h1, as1, ad1, N,
                                                     src, dst, E, bbase, pbase, part);
    bucket_build_k<<<NB, 512, 0, stream>>>(part, bbase, row_start, csr, N);

    // --- layer 1 aggregation ---
    aggregate1_k<<<ablocks, 256, 0, stream>>>((const uint2*)h1, as1, ad1, row_start,
                                              csr, b1, (uint2*)h1o, N);

    // --- layer 2 ---
    gemm2_k<<<g2blocks, 256, 0, stream>>>((const _Float16*)h1o, W2T, a_src2, a_dst2,
                                          h2f8, as2, ad2, N);
    aggregate2_k<<<ablocks, 256, 0, stream>>>((const uint2*)h2f8, as2, ad2,
                                              row_start, csr, b2, (float*)d_out, N);
}